// Round 5
// baseline (362.918 us; speedup 1.0000x reference)
//
#include <hip/hip_runtime.h>
#include <cstdint>
#include <cstddef>

typedef unsigned short u16;
typedef __attribute__((ext_vector_type(8))) short short8;
typedef __attribute__((ext_vector_type(4))) float floatx4;

#define DEVI __device__ __forceinline__

constexpr int Bb  = 2;
constexpr int Ss  = 2048;
constexpr int Hh  = 2048;
constexpr int NH  = 16;
constexpr int NKV = 4;
constexpr int HD  = 128;
constexpr int MROWS = Bb * Ss;  // 4096

DEVI u16 f2bf(float f) {
  union { float f; unsigned u; } v; v.f = f;
  unsigned r = v.u + 0x7fffu + ((v.u >> 16) & 1u);
  return (u16)(r >> 16);
}
DEVI float bf2f(u16 v) {
  union { unsigned u; float f; } x; x.u = ((unsigned)v) << 16; return x.f;
}
// pack two fp32 into (bf16(b)<<16)|bf16(a)
DEVI unsigned pkbf(float a, float b) {
  union { float f; unsigned u; } ua, ub; ua.f = a; ub.f = b;
  return __builtin_amdgcn_perm(ub.u + 0x8000u, ua.u + 0x8000u, 0x07060302u);
}

// async global->LDS, 16B per lane. LDS dest must be wave-uniform base + lane*16.
DEVI void llds16(const u16* g, u16* l) {
  __builtin_amdgcn_global_load_lds(
      (const __attribute__((address_space(1))) void*)g,
      (__attribute__((address_space(3))) void*)l, 16, 0, 0);
}

// ---------- fp32 -> bf16 convert (vectorized) ----------
__global__ void k_f2b(const float4* __restrict__ in, ushort4* __restrict__ out, int n4) {
  int i = blockIdx.x * blockDim.x + threadIdx.x;
  if (i < n4) {
    float4 v = in[i];
    ushort4 o;
    o.x = f2bf(v.x); o.y = f2bf(v.y); o.z = f2bf(v.z); o.w = f2bf(v.w);
    out[i] = o;
  }
}

// ---------- all 4 weight transposes in one launch: (K=2048,N) fp32 -> (N,K) bf16 ----------
__global__ void k_tw4(const float* __restrict__ wq, const float* __restrict__ wk,
                      const float* __restrict__ wv, const float* __restrict__ wo,
                      u16* __restrict__ wqkvT, u16* __restrict__ woT) {
  __shared__ float tile[32][33];
  const int K = 2048;
  int bx = blockIdx.x;   // 0..159
  const float* in; u16* outp; int N, nx;
  if (bx < 64)       { in = wq; outp = wqkvT;                       N = 2048; nx = bx; }
  else if (bx < 80)  { in = wk; outp = wqkvT + (size_t)2048 * 2048; N = 512;  nx = bx - 64; }
  else if (bx < 96)  { in = wv; outp = wqkvT + (size_t)2560 * 2048; N = 512;  nx = bx - 80; }
  else               { in = wo; outp = woT;                         N = 2048; nx = bx - 96; }
  int n0 = nx * 32, k0 = blockIdx.y * 32;
  int tx = threadIdx.x & 31, ty = threadIdx.x >> 5;  // 256 threads
  for (int i = ty; i < 32; i += 8)
    tile[i][tx] = in[(size_t)(k0 + i) * N + n0 + tx];
  __syncthreads();
  for (int i = ty; i < 32; i += 8)
    outp[(size_t)(n0 + i) * K + k0 + tx] = f2bf(tile[tx][i]);
}

// ---------- GEMM, BK=64, XOR-swizzled LDS: C(M,N) = A(M,K) bf16 @ Bt(N,K)^T bf16 ----------
// 128x128 tile, 256 threads / 4 waves, 16x16x32 bf16 MFMA; 32 MFMA/wave per barrier.
template <bool BF16_OUT>
__global__ __launch_bounds__(256) void k_gemm(const u16* __restrict__ A, const u16* __restrict__ Bt,
                                              void* __restrict__ Cv, int M, int N, int K) {
  __shared__ u16 As[128 * 64];
  __shared__ u16 Bs[128 * 64];
  const int t = threadIdx.x;
  const int lane = t & 63, w = t >> 6;
  const int q4 = lane >> 4, l16 = lane & 15;
  const int sw8 = l16 & 7;
  const int m0 = blockIdx.y * 128, n0 = blockIdx.x * 128;
  const int wm = (w >> 1) * 64, wn = (w & 1) * 64;

  floatx4 acc[4][4];
#pragma unroll
  for (int i = 0; i < 4; ++i)
#pragma unroll
    for (int j = 0; j < 4; ++j) acc[i][j] = floatx4{0.f, 0.f, 0.f, 0.f};

  const u16* Ab = A + (size_t)m0 * K;
  const u16* Bp = Bt + (size_t)n0 * K;

  for (int k0 = 0; k0 < K; k0 += 64) {
#pragma unroll
    for (int it = 0; it < 4; ++it) {
      int c = it * 256 + t;            // 1024 chunks of 8 elems per 128x64 tile
      int row = c >> 3, pc = c & 7;
      int gc = pc ^ (row & 7);         // swizzled source chunk
      llds16(Ab + (size_t)row * K + k0 + gc * 8, &As[c * 8]);
      llds16(Bp + (size_t)row * K + k0 + gc * 8, &Bs[c * 8]);
    }
    __syncthreads();
#pragma unroll
    for (int kt = 0; kt < 2; ++kt) {
      short8 af[4], bfr[4];
#pragma unroll
      for (int tm = 0; tm < 4; ++tm)
        af[tm] = *(const short8*)&As[(wm + tm * 16 + l16) * 64 + (((kt * 4 + q4)) ^ sw8) * 8];
#pragma unroll
      for (int tn = 0; tn < 4; ++tn)
        bfr[tn] = *(const short8*)&Bs[(wn + tn * 16 + l16) * 64 + (((kt * 4 + q4)) ^ sw8) * 8];
#pragma unroll
      for (int tm = 0; tm < 4; ++tm)
#pragma unroll
        for (int tn = 0; tn < 4; ++tn)
          acc[tm][tn] = __builtin_amdgcn_mfma_f32_16x16x32_bf16(af[tm], bfr[tn], acc[tm][tn], 0, 0, 0);
    }
    __syncthreads();
  }
  // C/D layout: col = lane&15, row = quad*4 + reg (m89-verified)
#pragma unroll
  for (int tm = 0; tm < 4; ++tm) {
    int rb = m0 + wm + tm * 16 + q4 * 4;
#pragma unroll
    for (int tn = 0; tn < 4; ++tn) {
      int col = n0 + wn + tn * 16 + l16;
#pragma unroll
      for (int r = 0; r < 4; ++r) {
        if constexpr (BF16_OUT)
          ((u16*)Cv)[(size_t)(rb + r) * N + col] = f2bf(acc[tm][tn][r]);
        else
          ((float*)Cv)[(size_t)(rb + r) * N + col] = acc[tm][tn][r];
      }
    }
  }
}

// ---------- RoPE Q+K in one launch: qkv bf16 (B,S,3072) -> qout (B,S,NH,HD), kout (B,S,NKV,HD) ----------
__global__ void k_rope2(const u16* __restrict__ qkv, u16* __restrict__ qout, u16* __restrict__ kout,
                        float qscale) {
  int idx = blockIdx.x * blockDim.x + threadIdx.x;
  int j = idx & 63;
  int tmp = idx >> 6;
  int hh = tmp % 20; tmp /= 20;   // tmp = b*S + s; hh 0..15 = Q head, 16..19 = K head
  int s = tmp % Ss;
  const u16* ip; u16* op; float scale;
  if (hh < 16) { ip = qkv + (size_t)tmp * 3072 + hh * HD;                op = qout + ((size_t)tmp * NH + hh) * HD;         scale = qscale; }
  else         { ip = qkv + (size_t)tmp * 3072 + 2048 + (hh - 16) * HD;  op = kout + ((size_t)tmp * NKV + (hh - 16)) * HD; scale = 1.0f; }
  float inv = exp2f(-(float)(2 * j) * (13.287712379549449f / (float)HD));
  float ang = (float)s * inv;
  float c = __cosf(ang), sn = __sinf(ang);   // fast v_sin/v_cos path
  float x1 = bf2f(ip[j]), x2 = bf2f(ip[j + 64]);
  op[j]      = f2bf((x1 * c - x2 * sn) * scale);
  op[j + 64] = f2bf((x2 * c + x1 * sn) * scale);
}

// ---------- V transpose: bf16 (B,S,cols of instride; coloff+g*HD+d) -> bf16 Vt (B,NKV,HD,S) ----------
__global__ void k_vt(const u16* __restrict__ V, u16* __restrict__ Vt, int instride, int coloff) {
  __shared__ u16 tile[32][33];
  int bg = blockIdx.z;                 // b*NKV + g
  int s0 = blockIdx.x * 32;
  int d0 = blockIdx.y * 32;
  int tx = threadIdx.x & 31, ty = threadIdx.x >> 5;
  int b = bg / NKV, g = bg % NKV;
  const u16* vin = V + (size_t)(b * Ss) * instride + coloff + g * HD;
  for (int i = ty; i < 32; i += 8)
    tile[i][tx] = vin[(size_t)(s0 + i) * instride + d0 + tx];
  __syncthreads();
  u16* vout = Vt + (size_t)bg * HD * Ss;
  for (int i = ty; i < 32; i += 8)
    vout[(size_t)(d0 + i) * Ss + s0 + tx] = tile[tx][i];
}

// ---------- flash attention, S^T formulation, unified dual-tile kb loop ----------
// Block handles q-tiles qbL=bx and qbH=31-bx in ONE kb loop: K/V staged once per kb,
// K/V register fragments shared between both tiles' MFMAs while kb<=qbL.
__global__ __launch_bounds__(256) void k_flash(const u16* __restrict__ Q, const u16* __restrict__ Kk,
                                               const u16* __restrict__ Vt, u16* __restrict__ O) {
  __shared__ u16 Kts[2][64 * 128];   // [sk][d], 16B-chunk XOR swizzled
  __shared__ u16 Vts[2][128 * 64];   // [d][sk], swizzled
  __shared__ u16 Ps[64 * 72];        // P^T [q][sk], rows padded to 72; reused H then L (wave-private)
  const int t = threadIdx.x, lane = t & 63, w = t >> 6;
  const int q4 = lane >> 4, l16 = lane & 15;
  const int sw8 = l16 & 7;
  const int h = blockIdx.y, b = blockIdx.z, g = h >> 2;  // NREP=4
  const u16* Qh = Q + ((size_t)b * Ss * NH + h) * HD;
  const u16* Kh = Kk + ((size_t)b * Ss * NKV + g) * HD;
  const u16* Vh = Vt + (size_t)(b * NKV + g) * HD * Ss;
  u16* Oh = O + ((size_t)b * Ss * NH + h) * HD;
  const int wl = w * 16 + l16;       // this lane's q within a 64-row tile

  auto stage = [&](int k0, int buf) {
#pragma unroll
    for (int it = 0; it < 4; ++it) {
      int c = it * 256 + t;
      int krow = c >> 4, kpc = c & 15;
      llds16(Kh + (size_t)(k0 + krow) * (NKV * HD) + (kpc ^ (krow & 7)) * 8, &Kts[buf][c * 8]);
      int vrow = c >> 3, vpc = c & 7;
      llds16(Vh + (size_t)vrow * Ss + k0 + (vpc ^ (vrow & 7)) * 8, &Vts[buf][c * 8]);
    }
  };

  const int qbL = blockIdx.x;        // 0..15
  const int qbH = 31 - qbL;          // 16..31
  const int qrowL = qbL * 64 + wl, qrowH = qbH * 64 + wl;

  short8 qfL[4], qfH[4];
#pragma unroll
  for (int kt = 0; kt < 4; ++kt) {
    qfL[kt] = *(const short8*)&Qh[(size_t)qrowL * (NH * HD) + kt * 32 + q4 * 8];
    qfH[kt] = *(const short8*)&Qh[(size_t)qrowH * (NH * HD) + kt * 32 + q4 * 8];
  }

  floatx4 oaL[8], oaH[8];
#pragma unroll
  for (int i = 0; i < 8; ++i) { oaL[i] = floatx4{0.f,0.f,0.f,0.f}; oaH[i] = floatx4{0.f,0.f,0.f,0.f}; }
  float mL = -1e30f, lL = 0.f, mH = -1e30f, lH = 0.f;

  // online softmax + P^T store for one tile (lane owns one q; base-2 domain)
  auto softmax_p = [&](floatx4 (&sc)[4], float& m_i, float& l_p, floatx4 (&oacc)[8]) {
    float vmax = sc[0][0];
#pragma unroll
    for (int tn = 0; tn < 4; ++tn)
#pragma unroll
      for (int r = 0; r < 4; ++r) vmax = fmaxf(vmax, sc[tn][r]);
    vmax = fmaxf(vmax, __shfl_xor(vmax, 16));
    vmax = fmaxf(vmax, __shfl_xor(vmax, 32));
    float mnew = fmaxf(m_i, vmax);
    float alpha = __builtin_amdgcn_exp2f(m_i - mnew);
    m_i = mnew;
    float rs = 0.f;
#pragma unroll
    for (int tn = 0; tn < 4; ++tn)
#pragma unroll
      for (int r = 0; r < 4; ++r) {
        float p = __builtin_amdgcn_exp2f(sc[tn][r] - mnew);
        sc[tn][r] = p;
        rs += p;
      }
    l_p = l_p * alpha + rs;
#pragma unroll
    for (int td = 0; td < 8; ++td) oacc[td] *= alpha;
#pragma unroll
    for (int tn = 0; tn < 4; ++tn) {
      uint2 pk;
      pk.x = pkbf(sc[tn][0], sc[tn][1]);
      pk.y = pkbf(sc[tn][2], sc[tn][3]);
      *(uint2*)&Ps[(size_t)wl * 72 + tn * 16 + q4 * 4] = pk;
    }
  };

  int cur = 0;
  stage(0, 0);

  for (int kb = 0; kb <= qbH; ++kb) {
    __syncthreads();
    if (kb < qbH) stage((kb + 1) * 64, cur ^ 1);
    const u16* Kb = Kts[cur];
    const u16* Vb = Vts[cur];
    const bool doL = (kb <= qbL);

    floatx4 scH[4], scL[4];
#pragma unroll
    for (int tn = 0; tn < 4; ++tn) { scH[tn] = floatx4{0.f,0.f,0.f,0.f}; scL[tn] = floatx4{0.f,0.f,0.f,0.f}; }

    if (doL) {
#pragma unroll
      for (int kt = 0; kt < 4; ++kt)
#pragma unroll
        for (int tn = 0; tn < 4; ++tn) {
          short8 kfr = *(const short8*)&Kb[(tn * 16 + l16) * 128 + ((kt * 4 + q4) ^ sw8) * 8];
          scH[tn] = __builtin_amdgcn_mfma_f32_16x16x32_bf16(kfr, qfH[kt], scH[tn], 0, 0, 0);
          scL[tn] = __builtin_amdgcn_mfma_f32_16x16x32_bf16(kfr, qfL[kt], scL[tn], 0, 0, 0);
        }
    } else {
#pragma unroll
      for (int kt = 0; kt < 4; ++kt)
#pragma unroll
        for (int tn = 0; tn < 4; ++tn) {
          short8 kfr = *(const short8*)&Kb[(tn * 16 + l16) * 128 + ((kt * 4 + q4) ^ sw8) * 8];
          scH[tn] = __builtin_amdgcn_mfma_f32_16x16x32_bf16(kfr, qfH[kt], scH[tn], 0, 0, 0);
        }
    }

    // diagonal masks (tile-local: key tn*16+q4*4+r vs q = wl)
    if (kb == qbH) {
#pragma unroll
      for (int tn = 0; tn < 4; ++tn) {
        int keyb = tn * 16 + q4 * 4;
#pragma unroll
        for (int r = 0; r < 4; ++r)
          if (keyb + r > wl) scH[tn][r] = -1e30f;
      }
    }
    if (kb == qbL) {
#pragma unroll
      for (int tn = 0; tn < 4; ++tn) {
        int keyb = tn * 16 + q4 * 4;
#pragma unroll
        for (int r = 0; r < 4; ++r)
          if (keyb + r > wl) scL[tn][r] = -1e30f;
      }
    }

    // softmax + P^T (H first, read its fragments, then L reuses Ps — wave-private, DS in-order)
    softmax_p(scH, mH, lH, oaH);
    short8 pfH[2], pfL[2];
#pragma unroll
    for (int kt2 = 0; kt2 < 2; ++kt2)
      pfH[kt2] = *(const short8*)&Ps[(size_t)wl * 72 + kt2 * 32 + q4 * 8];
    if (doL) {
      softmax_p(scL, mL, lL, oaL);
#pragma unroll
      for (int kt2 = 0; kt2 < 2; ++kt2)
        pfL[kt2] = *(const short8*)&Ps[(size_t)wl * 72 + kt2 * 32 + q4 * 8];
    }

    // O^T += V^T P^T, V fragments shared between tiles
    if (doL) {
#pragma unroll
      for (int kt2 = 0; kt2 < 2; ++kt2)
#pragma unroll
        for (int td = 0; td < 8; ++td) {
          short8 vfr = *(const short8*)&Vb[(td * 16 + l16) * 64 + ((kt2 * 4 + q4) ^ sw8) * 8];
          oaH[td] = __builtin_amdgcn_mfma_f32_16x16x32_bf16(vfr, pfH[kt2], oaH[td], 0, 0, 0);
          oaL[td] = __builtin_amdgcn_mfma_f32_16x16x32_bf16(vfr, pfL[kt2], oaL[td], 0, 0, 0);
        }
    } else {
#pragma unroll
      for (int kt2 = 0; kt2 < 2; ++kt2)
#pragma unroll
        for (int td = 0; td < 8; ++td) {
          short8 vfr = *(const short8*)&Vb[(td * 16 + l16) * 64 + ((kt2 * 4 + q4) ^ sw8) * 8];
          oaH[td] = __builtin_amdgcn_mfma_f32_16x16x32_bf16(vfr, pfH[kt2], oaH[td], 0, 0, 0);
        }
    }
    cur ^= 1;
  }

  // epilogues
  auto epi = [&](floatx4 (&oacc)[8], float l_p, int qrow) {
    float l = l_p;
    l += __shfl_xor(l, 16);
    l += __shfl_xor(l, 32);
    float linv = 1.f / l;
#pragma unroll
    for (int td = 0; td < 8; ++td) {
      uint2 pk;
      pk.x = pkbf(oacc[td][0] * linv, oacc[td][1] * linv);
      pk.y = pkbf(oacc[td][2] * linv, oacc[td][3] * linv);
      *(uint2*)&Oh[(size_t)qrow * (NH * HD) + td * 16 + q4 * 4] = pk;
    }
  };
  epi(oaH, lH, qrowH);
  epi(oaL, lL, qrowL);
}

extern "C" void kernel_launch(void* const* d_in, const int* in_sizes, int n_in,
                              void* d_out, int out_size, void* d_ws, size_t ws_size,
                              hipStream_t stream) {
  (void)in_sizes; (void)n_in; (void)out_size; (void)ws_size;
  const float* x  = (const float*)d_in[0];
  const float* wq = (const float*)d_in[1];
  const float* wk = (const float*)d_in[2];
  const float* wv = (const float*)d_in[3];
  const float* wo = (const float*)d_in[4];
  float* out = (float*)d_out;

  char* ws = (char*)d_ws;
  size_t off = 0;
  auto alloc = [&](size_t bytes) {
    char* p = ws + off;
    off += (bytes + 255) & ~(size_t)255;
    return (void*)p;
  };
  u16* xb     = (u16*)alloc((size_t)MROWS * Hh * 2);        // reused as O (bf16) later
  u16* wqkvT  = (u16*)alloc((size_t)3072 * 2048 * 2);       // [wqT | wkT | wvT]
  u16* woT    = (u16*)alloc((size_t)2048 * 2048 * 2);
  u16* qkv16  = (u16*)alloc((size_t)MROWS * 3072 * 2);      // fused projection output, bf16
  u16* qb16   = (u16*)alloc((size_t)MROWS * 2048 * 2);
  u16* kb16   = (u16*)alloc((size_t)MROWS * 512 * 2);
  u16* vt16   = (u16*)alloc((size_t)MROWS * 512 * 2);
  u16* o16    = xb;  // xb dead after QKV projection

  // 1. x -> bf16
  k_f2b<<<dim3((MROWS * Hh / 4 + 255) / 256), dim3(256), 0, stream>>>(
      (const float4*)x, (ushort4*)xb, MROWS * Hh / 4);
  // 2. all weight transposes, one launch
  k_tw4<<<dim3(160, 64), dim3(256), 0, stream>>>(wq, wk, wv, wo, wqkvT, woT);
  // 3. fused QKV projection -> bf16 (4096,3072)
  k_gemm<true><<<dim3(24, 32), dim3(256), 0, stream>>>(xb, wqkvT, qkv16, MROWS, 3072, 2048);
  // 4. RoPE Q+K, one launch; Q scale folds 1/sqrt(HD)*log2(e) (flash in base-2 domain)
  k_rope2<<<dim3(Bb * Ss * 20 * 64 / 256), dim3(256), 0, stream>>>(
      qkv16, qb16, kb16, 0.08838834764831845f * 1.4426950408889634f);
  // 5. V -> (B,NKV,HD,S) bf16
  k_vt<<<dim3(Ss / 32, HD / 32, Bb * NKV), dim3(256), 0, stream>>>(qkv16, vt16, 3072, 2560);
  // 6. flash attention (unified dual-tile)
  k_flash<<<dim3(16, NH, Bb), dim3(256), 0, stream>>>(qb16, kb16, vt16, o16);
  // 7. output projection -> fp32 out
  k_gemm<false><<<dim3(16, 32), dim3(256), 0, stream>>>(o16, woT, out, MROWS, 2048, 2048);
}

// Round 6
// 310.001 us; speedup vs baseline: 1.1707x; 1.1707x over previous
//
#include <hip/hip_runtime.h>
#include <cstdint>
#include <cstddef>

typedef unsigned short u16;
typedef __attribute__((ext_vector_type(8))) short short8;
typedef __attribute__((ext_vector_type(4))) float floatx4;

#define DEVI __device__ __forceinline__

constexpr int Bb  = 2;
constexpr int Ss  = 2048;
constexpr int Hh  = 2048;
constexpr int NH  = 16;
constexpr int NKV = 4;
constexpr int HD  = 128;
constexpr int MROWS = Bb * Ss;  // 4096

DEVI u16 f2bf(float f) {
  union { float f; unsigned u; } v; v.f = f;
  unsigned r = v.u + 0x7fffu + ((v.u >> 16) & 1u);
  return (u16)(r >> 16);
}
DEVI float bf2f(u16 v) {
  union { unsigned u; float f; } x; x.u = ((unsigned)v) << 16; return x.f;
}
// pack two fp32 into (bf16(b)<<16)|bf16(a)
DEVI unsigned pkbf(float a, float b) {
  union { float f; unsigned u; } ua, ub; ua.f = a; ub.f = b;
  return __builtin_amdgcn_perm(ub.u + 0x8000u, ua.u + 0x8000u, 0x07060302u);
}

// async global->LDS, 16B per lane. LDS dest must be wave-uniform base + lane*16.
DEVI void llds16(const u16* g, u16* l) {
  __builtin_amdgcn_global_load_lds(
      (const __attribute__((address_space(1))) void*)g,
      (__attribute__((address_space(3))) void*)l, 16, 0, 0);
}

// ---------- fp32 -> bf16 convert (vectorized) ----------
__global__ void k_f2b(const float4* __restrict__ in, ushort4* __restrict__ out, int n4) {
  int i = blockIdx.x * blockDim.x + threadIdx.x;
  if (i < n4) {
    float4 v = in[i];
    ushort4 o;
    o.x = f2bf(v.x); o.y = f2bf(v.y); o.z = f2bf(v.z); o.w = f2bf(v.w);
    out[i] = o;
  }
}

// ---------- all 4 weight transposes in one launch: (K=2048,N) fp32 -> (N,K) bf16 ----------
__global__ void k_tw4(const float* __restrict__ wq, const float* __restrict__ wk,
                      const float* __restrict__ wv, const float* __restrict__ wo,
                      u16* __restrict__ wqkvT, u16* __restrict__ woT) {
  __shared__ float tile[32][33];
  const int K = 2048;
  int bx = blockIdx.x;   // 0..159
  const float* in; u16* outp; int N, nx;
  if (bx < 64)       { in = wq; outp = wqkvT;                       N = 2048; nx = bx; }
  else if (bx < 80)  { in = wk; outp = wqkvT + (size_t)2048 * 2048; N = 512;  nx = bx - 64; }
  else if (bx < 96)  { in = wv; outp = wqkvT + (size_t)2560 * 2048; N = 512;  nx = bx - 80; }
  else               { in = wo; outp = woT;                         N = 2048; nx = bx - 96; }
  int n0 = nx * 32, k0 = blockIdx.y * 32;
  int tx = threadIdx.x & 31, ty = threadIdx.x >> 5;  // 256 threads
  for (int i = ty; i < 32; i += 8)
    tile[i][tx] = in[(size_t)(k0 + i) * N + n0 + tx];
  __syncthreads();
  for (int i = ty; i < 32; i += 8)
    outp[(size_t)(n0 + i) * K + k0 + tx] = f2bf(tile[tx][i]);
}

// ---------- GEMM, BK=64, XOR-swizzled LDS: C(M,N) = A(M,K) bf16 @ Bt(N,K)^T bf16 ----------
// 128x128 tile, 256 threads / 4 waves, 16x16x32 bf16 MFMA; 32 MFMA/wave per barrier.
template <bool BF16_OUT>
__global__ __launch_bounds__(256) void k_gemm(const u16* __restrict__ A, const u16* __restrict__ Bt,
                                              void* __restrict__ Cv, int M, int N, int K) {
  __shared__ u16 As[128 * 64];
  __shared__ u16 Bs[128 * 64];
  const int t = threadIdx.x;
  const int lane = t & 63, w = t >> 6;
  const int q4 = lane >> 4, l16 = lane & 15;
  const int sw8 = l16 & 7;
  const int m0 = blockIdx.y * 128, n0 = blockIdx.x * 128;
  const int wm = (w >> 1) * 64, wn = (w & 1) * 64;

  floatx4 acc[4][4];
#pragma unroll
  for (int i = 0; i < 4; ++i)
#pragma unroll
    for (int j = 0; j < 4; ++j) acc[i][j] = floatx4{0.f, 0.f, 0.f, 0.f};

  const u16* Ab = A + (size_t)m0 * K;
  const u16* Bp = Bt + (size_t)n0 * K;

  for (int k0 = 0; k0 < K; k0 += 64) {
#pragma unroll
    for (int it = 0; it < 4; ++it) {
      int c = it * 256 + t;            // 1024 chunks of 8 elems per 128x64 tile
      int row = c >> 3, pc = c & 7;
      int gc = pc ^ (row & 7);         // swizzled source chunk
      llds16(Ab + (size_t)row * K + k0 + gc * 8, &As[c * 8]);
      llds16(Bp + (size_t)row * K + k0 + gc * 8, &Bs[c * 8]);
    }
    __syncthreads();
#pragma unroll
    for (int kt = 0; kt < 2; ++kt) {
      short8 af[4], bfr[4];
#pragma unroll
      for (int tm = 0; tm < 4; ++tm)
        af[tm] = *(const short8*)&As[(wm + tm * 16 + l16) * 64 + (((kt * 4 + q4)) ^ sw8) * 8];
#pragma unroll
      for (int tn = 0; tn < 4; ++tn)
        bfr[tn] = *(const short8*)&Bs[(wn + tn * 16 + l16) * 64 + (((kt * 4 + q4)) ^ sw8) * 8];
#pragma unroll
      for (int tm = 0; tm < 4; ++tm)
#pragma unroll
        for (int tn = 0; tn < 4; ++tn)
          acc[tm][tn] = __builtin_amdgcn_mfma_f32_16x16x32_bf16(af[tm], bfr[tn], acc[tm][tn], 0, 0, 0);
    }
    __syncthreads();
  }
  // C/D layout: col = lane&15, row = quad*4 + reg (m89-verified)
#pragma unroll
  for (int tm = 0; tm < 4; ++tm) {
    int rb = m0 + wm + tm * 16 + q4 * 4;
#pragma unroll
    for (int tn = 0; tn < 4; ++tn) {
      int col = n0 + wn + tn * 16 + l16;
#pragma unroll
      for (int r = 0; r < 4; ++r) {
        if constexpr (BF16_OUT)
          ((u16*)Cv)[(size_t)(rb + r) * N + col] = f2bf(acc[tm][tn][r]);
        else
          ((float*)Cv)[(size_t)(rb + r) * N + col] = acc[tm][tn][r];
      }
    }
  }
}

// ---------- RoPE Q+K in one launch: qkv bf16 (B,S,3072) -> qout (B,S,NH,HD), kout (B,S,NKV,HD) ----------
__global__ void k_rope2(const u16* __restrict__ qkv, u16* __restrict__ qout, u16* __restrict__ kout,
                        float qscale) {
  int idx = blockIdx.x * blockDim.x + threadIdx.x;
  int j = idx & 63;
  int tmp = idx >> 6;
  int hh = tmp % 20; tmp /= 20;   // tmp = b*S + s; hh 0..15 = Q head, 16..19 = K head
  int s = tmp % Ss;
  const u16* ip; u16* op; float scale;
  if (hh < 16) { ip = qkv + (size_t)tmp * 3072 + hh * HD;                op = qout + ((size_t)tmp * NH + hh) * HD;         scale = qscale; }
  else         { ip = qkv + (size_t)tmp * 3072 + 2048 + (hh - 16) * HD;  op = kout + ((size_t)tmp * NKV + (hh - 16)) * HD; scale = 1.0f; }
  float inv = exp2f(-(float)(2 * j) * (13.287712379549449f / (float)HD));
  float ang = (float)s * inv;
  float c = __cosf(ang), sn = __sinf(ang);   // fast v_sin/v_cos path
  float x1 = bf2f(ip[j]), x2 = bf2f(ip[j + 64]);
  op[j]      = f2bf((x1 * c - x2 * sn) * scale);
  op[j + 64] = f2bf((x2 * c + x1 * sn) * scale);
}

// ---------- V transpose: bf16 (B,S,cols of instride; coloff+g*HD+d) -> bf16 Vt (B,NKV,HD,S) ----------
__global__ void k_vt(const u16* __restrict__ V, u16* __restrict__ Vt, int instride, int coloff) {
  __shared__ u16 tile[32][33];
  int bg = blockIdx.z;                 // b*NKV + g
  int s0 = blockIdx.x * 32;
  int d0 = blockIdx.y * 32;
  int tx = threadIdx.x & 31, ty = threadIdx.x >> 5;
  int b = bg / NKV, g = bg % NKV;
  const u16* vin = V + (size_t)(b * Ss) * instride + coloff + g * HD;
  for (int i = ty; i < 32; i += 8)
    tile[i][tx] = vin[(size_t)(s0 + i) * instride + d0 + tx];
  __syncthreads();
  u16* vout = Vt + (size_t)bg * HD * Ss;
  for (int i = ty; i < 32; i += 8)
    vout[(size_t)(d0 + i) * Ss + s0 + tx] = tile[tx][i];
}

// ---------- flash attention, S^T formulation (R3 version — low VGPR, balanced pair via hf loop) ----------
// Q pre-scaled by log2(e)/sqrt(HD); scores in base-2 domain. Each lane owns ONE q-column.
// S^T = K Q^T via mfma(kfrag, qfrag): C tile [key][q]; O^T = V^T P^T via mfma(vfrag, pfrag).
__global__ __launch_bounds__(256) void k_flash(const u16* __restrict__ Q, const u16* __restrict__ Kk,
                                               const u16* __restrict__ Vt, u16* __restrict__ O) {
  __shared__ u16 Kts[2][64 * 128];   // [sk][d], 16B-chunk XOR swizzled
  __shared__ u16 Vts[2][128 * 64];   // [d][sk], swizzled
  __shared__ u16 Ps[64 * 72];        // P^T [q][sk], rows padded to 72
  const int t = threadIdx.x, lane = t & 63, w = t >> 6;
  const int q4 = lane >> 4, l16 = lane & 15;
  const int sw8 = l16 & 7;
  const int h = blockIdx.y, b = blockIdx.z, g = h >> 2;  // NREP=4
  const u16* Qh = Q + ((size_t)b * Ss * NH + h) * HD;
  const u16* Kh = Kk + ((size_t)b * Ss * NKV + g) * HD;
  const u16* Vh = Vt + (size_t)(b * NKV + g) * HD * Ss;
  u16* Oh = O + ((size_t)b * Ss * NH + h) * HD;
  const int wl = w * 16 + l16;       // this lane's q within the 64-row tile

  auto stage = [&](int k0, int buf) {
#pragma unroll
    for (int it = 0; it < 4; ++it) {
      int c = it * 256 + t;                       // 1024 chunks each
      int krow = c >> 4, kpc = c & 15;
      llds16(Kh + (size_t)(k0 + krow) * (NKV * HD) + (kpc ^ (krow & 7)) * 8, &Kts[buf][c * 8]);
      int vrow = c >> 3, vpc = c & 7;
      llds16(Vh + (size_t)vrow * Ss + k0 + (vpc ^ (vrow & 7)) * 8, &Vts[buf][c * 8]);
    }
  };

  int cur = 0;
  for (int hf = 0; hf < 2; ++hf) {
    const int qb = hf ? (31 - (int)blockIdx.x) : (int)blockIdx.x;
    const int q0 = qb * 64;
    // Q fragment (loop-invariant): B-operand B[n=q=l16][k=d=q4*8+j]
    const int qrow = q0 + wl;
    short8 qf[4];
#pragma unroll
    for (int kt = 0; kt < 4; ++kt)
      qf[kt] = *(const short8*)&Qh[(size_t)qrow * (NH * HD) + kt * 32 + q4 * 8];

    floatx4 oacc[8];                  // O^T: d = td*16 + q4*4 + r, q = wl (this lane's)
#pragma unroll
    for (int i = 0; i < 8; ++i) oacc[i] = floatx4{0.f, 0.f, 0.f, 0.f};
    float m_i = -1e30f, l_p = 0.f;    // single q-row state per lane

    stage(0, cur);

    for (int kb = 0; kb <= qb; ++kb) {
      __syncthreads();
      if (kb < qb) stage((kb + 1) * 64, cur ^ 1);
      const u16* Kb = Kts[cur];
      const u16* Vb = Vts[cur];

      // S^T = K Q^T : keys (rows) x 16 q (cols); per lane: keys tn*16+q4*4+r, q = wl
      floatx4 sc[4];
#pragma unroll
      for (int tn = 0; tn < 4; ++tn) sc[tn] = floatx4{0.f, 0.f, 0.f, 0.f};
#pragma unroll
      for (int kt = 0; kt < 4; ++kt)
#pragma unroll
        for (int tn = 0; tn < 4; ++tn) {
          short8 kfr = *(const short8*)&Kb[(tn * 16 + l16) * 128 + ((kt * 4 + q4) ^ sw8) * 8];
          sc[tn] = __builtin_amdgcn_mfma_f32_16x16x32_bf16(kfr, qf[kt], sc[tn], 0, 0, 0);
        }

      if (kb == qb) {  // diagonal: mask key > q (both tile-local)
#pragma unroll
        for (int tn = 0; tn < 4; ++tn) {
          int keyb = tn * 16 + q4 * 4;
#pragma unroll
          for (int r = 0; r < 4; ++r)
            if (keyb + r > wl) sc[tn][r] = -1e30f;
        }
      }

      // online softmax (base-2): lane reduces its 16 keys, then across quads (^16, ^32)
      float vmax = sc[0][0];
#pragma unroll
      for (int tn = 0; tn < 4; ++tn)
#pragma unroll
        for (int r = 0; r < 4; ++r) vmax = fmaxf(vmax, sc[tn][r]);
      vmax = fmaxf(vmax, __shfl_xor(vmax, 16));
      vmax = fmaxf(vmax, __shfl_xor(vmax, 32));
      float mnew = fmaxf(m_i, vmax);
      float alpha = __builtin_amdgcn_exp2f(m_i - mnew);
      m_i = mnew;
      float rs = 0.f;
#pragma unroll
      for (int tn = 0; tn < 4; ++tn)
#pragma unroll
        for (int r = 0; r < 4; ++r) {
          float p = __builtin_amdgcn_exp2f(sc[tn][r] - mnew);
          sc[tn][r] = p;
          rs += p;
        }
      l_p = l_p * alpha + rs;          // per-lane partial (quad-reduced at end)
#pragma unroll
      for (int td = 0; td < 8; ++td) oacc[td] *= alpha;

      // P^T store: lane's 4 consecutive keys per tn -> packed b64, row = wl (wave-private)
#pragma unroll
      for (int tn = 0; tn < 4; ++tn) {
        uint2 pk;
        pk.x = pkbf(sc[tn][0], sc[tn][1]);
        pk.y = pkbf(sc[tn][2], sc[tn][3]);
        *(uint2*)&Ps[(size_t)wl * 72 + tn * 16 + q4 * 4] = pk;
      }

      // O^T += V^T P^T
#pragma unroll
      for (int kt2 = 0; kt2 < 2; ++kt2) {
        short8 pfr = *(const short8*)&Ps[(size_t)wl * 72 + kt2 * 32 + q4 * 8];
#pragma unroll
        for (int td = 0; td < 8; ++td) {
          short8 vfr = *(const short8*)&Vb[(td * 16 + l16) * 64 + ((kt2 * 4 + q4) ^ sw8) * 8];
          oacc[td] = __builtin_amdgcn_mfma_f32_16x16x32_bf16(vfr, pfr, oacc[td], 0, 0, 0);
        }
      }
      cur ^= 1;
    }

    // final denominator: reduce partials across quads
    float l = l_p;
    l += __shfl_xor(l, 16);
    l += __shfl_xor(l, 32);
    float linv = 1.f / l;
    // epilogue: lane owns q-row qrow; d = td*16 + q4*4 + r -> 4 consecutive bf16 = 8B store
#pragma unroll
    for (int td = 0; td < 8; ++td) {
      uint2 pk;
      pk.x = pkbf(oacc[td][0] * linv, oacc[td][1] * linv);
      pk.y = pkbf(oacc[td][2] * linv, oacc[td][3] * linv);
      *(uint2*)&Oh[(size_t)qrow * (NH * HD) + td * 16 + q4 * 4] = pk;
    }
  }
}

extern "C" void kernel_launch(void* const* d_in, const int* in_sizes, int n_in,
                              void* d_out, int out_size, void* d_ws, size_t ws_size,
                              hipStream_t stream) {
  (void)in_sizes; (void)n_in; (void)out_size; (void)ws_size;
  const float* x  = (const float*)d_in[0];
  const float* wq = (const float*)d_in[1];
  const float* wk = (const float*)d_in[2];
  const float* wv = (const float*)d_in[3];
  const float* wo = (const float*)d_in[4];
  float* out = (float*)d_out;

  char* ws = (char*)d_ws;
  size_t off = 0;
  auto alloc = [&](size_t bytes) {
    char* p = ws + off;
    off += (bytes + 255) & ~(size_t)255;
    return (void*)p;
  };
  u16* xb     = (u16*)alloc((size_t)MROWS * Hh * 2);        // reused as O (bf16) later
  u16* wqkvT  = (u16*)alloc((size_t)3072 * 2048 * 2);       // [wqT | wkT | wvT]
  u16* woT    = (u16*)alloc((size_t)2048 * 2048 * 2);
  u16* qkv16  = (u16*)alloc((size_t)MROWS * 3072 * 2);      // fused projection output, bf16
  u16* qb16   = (u16*)alloc((size_t)MROWS * 2048 * 2);
  u16* kb16   = (u16*)alloc((size_t)MROWS * 512 * 2);
  u16* vt16   = (u16*)alloc((size_t)MROWS * 512 * 2);
  u16* o16    = xb;  // xb dead after QKV projection

  // 1. x -> bf16
  k_f2b<<<dim3((MROWS * Hh / 4 + 255) / 256), dim3(256), 0, stream>>>(
      (const float4*)x, (ushort4*)xb, MROWS * Hh / 4);
  // 2. all weight transposes, one launch
  k_tw4<<<dim3(160, 64), dim3(256), 0, stream>>>(wq, wk, wv, wo, wqkvT, woT);
  // 3. fused QKV projection -> bf16 (4096,3072)
  k_gemm<true><<<dim3(24, 32), dim3(256), 0, stream>>>(xb, wqkvT, qkv16, MROWS, 3072, 2048);
  // 4. RoPE Q+K, one launch; Q scale folds 1/sqrt(HD)*log2(e) (flash in base-2 domain)
  k_rope2<<<dim3(Bb * Ss * 20 * 64 / 256), dim3(256), 0, stream>>>(
      qkv16, qb16, kb16, 0.08838834764831845f * 1.4426950408889634f);
  // 5. V -> (B,NKV,HD,S) bf16
  k_vt<<<dim3(Ss / 32, HD / 32, Bb * NKV), dim3(256), 0, stream>>>(qkv16, vt16, 3072, 2560);
  // 6. flash attention (R3 structure: pair via hf loop, one tile's state live at a time)
  k_flash<<<dim3(16, NH, Bb), dim3(256), 0, stream>>>(qb16, kb16, vt16, o16);
  // 7. output projection -> fp32 out
  k_gemm<false><<<dim3(16, 32), dim3(256), 0, stream>>>(o16, woT, out, MROWS, 2048, 2048);
}

// Round 7
// 301.393 us; speedup vs baseline: 1.2041x; 1.0286x over previous
//
#include <hip/hip_runtime.h>
#include <cstdint>
#include <cstddef>

typedef unsigned short u16;
typedef __attribute__((ext_vector_type(8))) short short8;
typedef __attribute__((ext_vector_type(4))) float floatx4;

#define DEVI __device__ __forceinline__

constexpr int Bb  = 2;
constexpr int Ss  = 2048;
constexpr int Hh  = 2048;
constexpr int NH  = 16;
constexpr int NKV = 4;
constexpr int HD  = 128;
constexpr int MROWS = Bb * Ss;  // 4096

DEVI u16 f2bf(float f) {
  union { float f; unsigned u; } v; v.f = f;
  unsigned r = v.u + 0x7fffu + ((v.u >> 16) & 1u);
  return (u16)(r >> 16);
}
DEVI float bf2f(u16 v) {
  union { unsigned u; float f; } x; x.u = ((unsigned)v) << 16; return x.f;
}
// pack two fp32 into (bf16(b)<<16)|bf16(a)
DEVI unsigned pkbf(float a, float b) {
  union { float f; unsigned u; } ua, ub; ua.f = a; ub.f = b;
  return __builtin_amdgcn_perm(ub.u + 0x8000u, ua.u + 0x8000u, 0x07060302u);
}

// async global->LDS, 16B per lane. LDS dest must be wave-uniform base + lane*16.
DEVI void llds16(const u16* g, u16* l) {
  __builtin_amdgcn_global_load_lds(
      (const __attribute__((address_space(1))) void*)g,
      (__attribute__((address_space(3))) void*)l, 16, 0, 0);
}

// ---------- prep: x->bf16 (blocks 0..8191) + 4 weight transposes (blocks 8192..18431) ----------
__global__ void k_prep(const float* __restrict__ x, const float* __restrict__ wq,
                       const float* __restrict__ wk, const float* __restrict__ wv,
                       const float* __restrict__ wo,
                       u16* __restrict__ xb, u16* __restrict__ wqkvT, u16* __restrict__ woT) {
  __shared__ float tile[32][33];
  int blk = blockIdx.x;
  if (blk < 8192) {            // f2b: 2,097,152 float4
    int i = blk * 256 + threadIdx.x;
    float4 v = ((const float4*)x)[i];
    ushort4 o;
    o.x = f2bf(v.x); o.y = f2bf(v.y); o.z = f2bf(v.z); o.w = f2bf(v.w);
    ((ushort4*)xb)[i] = o;
    return;
  }
  int idx = blk - 8192;        // 0..10239
  int bx = idx % 160, ky = idx / 160;   // bx: which 32-col strip, ky: which 32-row strip
  const int K = 2048;
  const float* in; u16* outp; int N, nx;
  if (bx < 64)       { in = wq; outp = wqkvT;                       N = 2048; nx = bx; }
  else if (bx < 80)  { in = wk; outp = wqkvT + (size_t)2048 * 2048; N = 512;  nx = bx - 64; }
  else if (bx < 96)  { in = wv; outp = wqkvT + (size_t)2560 * 2048; N = 512;  nx = bx - 80; }
  else               { in = wo; outp = woT;                         N = 2048; nx = bx - 96; }
  int n0 = nx * 32, k0 = ky * 32;
  int tx = threadIdx.x & 31, ty = threadIdx.x >> 5;
  for (int i = ty; i < 32; i += 8)
    tile[i][tx] = in[(size_t)(k0 + i) * N + n0 + tx];
  __syncthreads();
  for (int i = ty; i < 32; i += 8)
    outp[(size_t)(n0 + i) * K + k0 + tx] = f2bf(tile[tx][i]);
}

// ---------- GEMM, BK=64, XOR-swizzled LDS: C(M,N) = A(M,K) bf16 @ Bt(N,K)^T bf16 ----------
// 128x128 tile, 256 threads / 4 waves, 16x16x32 bf16 MFMA; 32 MFMA/wave per barrier.
template <bool BF16_OUT>
__global__ __launch_bounds__(256) void k_gemm(const u16* __restrict__ A, const u16* __restrict__ Bt,
                                              void* __restrict__ Cv, int M, int N, int K) {
  __shared__ u16 As[128 * 64];
  __shared__ u16 Bs[128 * 64];
  const int t = threadIdx.x;
  const int lane = t & 63, w = t >> 6;
  const int q4 = lane >> 4, l16 = lane & 15;
  const int sw8 = l16 & 7;
  const int m0 = blockIdx.y * 128, n0 = blockIdx.x * 128;
  const int wm = (w >> 1) * 64, wn = (w & 1) * 64;

  floatx4 acc[4][4];
#pragma unroll
  for (int i = 0; i < 4; ++i)
#pragma unroll
    for (int j = 0; j < 4; ++j) acc[i][j] = floatx4{0.f, 0.f, 0.f, 0.f};

  const u16* Ab = A + (size_t)m0 * K;
  const u16* Bp = Bt + (size_t)n0 * K;

  for (int k0 = 0; k0 < K; k0 += 64) {
#pragma unroll
    for (int it = 0; it < 4; ++it) {
      int c = it * 256 + t;            // 1024 chunks of 8 elems per 128x64 tile
      int row = c >> 3, pc = c & 7;
      int gc = pc ^ (row & 7);         // swizzled source chunk
      llds16(Ab + (size_t)row * K + k0 + gc * 8, &As[c * 8]);
      llds16(Bp + (size_t)row * K + k0 + gc * 8, &Bs[c * 8]);
    }
    __syncthreads();
#pragma unroll
    for (int kt = 0; kt < 2; ++kt) {
      short8 af[4], bfr[4];
#pragma unroll
      for (int tm = 0; tm < 4; ++tm)
        af[tm] = *(const short8*)&As[(wm + tm * 16 + l16) * 64 + (((kt * 4 + q4)) ^ sw8) * 8];
#pragma unroll
      for (int tn = 0; tn < 4; ++tn)
        bfr[tn] = *(const short8*)&Bs[(wn + tn * 16 + l16) * 64 + (((kt * 4 + q4)) ^ sw8) * 8];
#pragma unroll
      for (int tm = 0; tm < 4; ++tm)
#pragma unroll
        for (int tn = 0; tn < 4; ++tn)
          acc[tm][tn] = __builtin_amdgcn_mfma_f32_16x16x32_bf16(af[tm], bfr[tn], acc[tm][tn], 0, 0, 0);
    }
    __syncthreads();
  }
  // C/D layout: col = lane&15, row = quad*4 + reg (m89-verified)
#pragma unroll
  for (int tm = 0; tm < 4; ++tm) {
    int rb = m0 + wm + tm * 16 + q4 * 4;
#pragma unroll
    for (int tn = 0; tn < 4; ++tn) {
      int col = n0 + wn + tn * 16 + l16;
#pragma unroll
      for (int r = 0; r < 4; ++r) {
        if constexpr (BF16_OUT)
          ((u16*)Cv)[(size_t)(rb + r) * N + col] = f2bf(acc[tm][tn][r]);
        else
          ((float*)Cv)[(size_t)(rb + r) * N + col] = acc[tm][tn][r];
      }
    }
  }
}

// ---------- post: RoPE Q+K (blocks 0..20479) + V transpose (blocks 20480..22527) ----------
__global__ void k_post(const u16* __restrict__ qkv, u16* __restrict__ qout, u16* __restrict__ kout,
                       u16* __restrict__ Vt, float qscale) {
  __shared__ u16 tile[32][33];
  int blk = blockIdx.x;
  if (blk < 20480) {           // RoPE: B*S*20 head-slots * 64 lanes-j
    int idx = blk * 256 + threadIdx.x;
    int j = idx & 63;
    int tmp = idx >> 6;
    int hh = tmp % 20; tmp /= 20;   // tmp = b*S + s
    int s = tmp & (Ss - 1);
    const u16* ip; u16* op; float scale;
    if (hh < 16) { ip = qkv + (size_t)tmp * 3072 + hh * HD;                op = qout + ((size_t)tmp * NH + hh) * HD;         scale = qscale; }
    else         { ip = qkv + (size_t)tmp * 3072 + 2048 + (hh - 16) * HD;  op = kout + ((size_t)tmp * NKV + (hh - 16)) * HD; scale = 1.0f; }
    float inv = exp2f(-(float)(2 * j) * (13.287712379549449f / (float)HD));
    float ang = (float)s * inv;
    float c = __cosf(ang), sn = __sinf(ang);
    float x1 = bf2f(ip[j]), x2 = bf2f(ip[j + 64]);
    op[j]      = f2bf((x1 * c - x2 * sn) * scale);
    op[j + 64] = f2bf((x2 * c + x1 * sn) * scale);
    return;
  }
  int vidx = blk - 20480;      // 0..2047: (s_blk 64) x (d_blk 4) x (bg 8)
  int s0 = (vidx & 63) * 32;
  int d0 = ((vidx >> 6) & 3) * 32;
  int bg = vidx >> 8;          // b*NKV + g
  int tx = threadIdx.x & 31, ty = threadIdx.x >> 5;
  int b = bg >> 2, g = bg & 3;
  const u16* vin = qkv + (size_t)(b * Ss) * 3072 + 2560 + g * HD;
  for (int i = ty; i < 32; i += 8)
    tile[i][tx] = vin[(size_t)(s0 + i) * 3072 + d0 + tx];
  __syncthreads();
  u16* vout = Vt + (size_t)bg * HD * Ss;
  for (int i = ty; i < 32; i += 8)
    vout[(size_t)(d0 + i) * Ss + s0 + tx] = tile[tx][i];
}

// ---------- flash attention, S^T formulation, single-buffered K/V (41.25 KB LDS -> 3 blocks/CU) ----------
// Q pre-scaled by log2(e)/sqrt(HD); scores in base-2 domain. Each lane owns ONE q-column.
// S^T = K Q^T via mfma(kfrag, qfrag): C tile [key][q]; O^T = V^T P^T via mfma(vfrag, pfrag).
// m97-style 2-barrier K-loop: cross-BLOCK overlap (3 blocks/CU) hides the staging drain.
__global__ __launch_bounds__(256) void k_flash(const u16* __restrict__ Q, const u16* __restrict__ Kk,
                                               const u16* __restrict__ Vt, u16* __restrict__ O) {
  __shared__ u16 Kts[64 * 128];   // [sk][d], 16B-chunk XOR swizzled
  __shared__ u16 Vts[128 * 64];   // [d][sk], swizzled
  __shared__ u16 Ps[64 * 72];     // P^T [q][sk], rows padded to 72
  const int t = threadIdx.x, lane = t & 63, w = t >> 6;
  const int q4 = lane >> 4, l16 = lane & 15;
  const int sw8 = l16 & 7;
  const int h = blockIdx.y, b = blockIdx.z, g = h >> 2;  // NREP=4
  const u16* Qh = Q + ((size_t)b * Ss * NH + h) * HD;
  const u16* Kh = Kk + ((size_t)b * Ss * NKV + g) * HD;
  const u16* Vh = Vt + (size_t)(b * NKV + g) * HD * Ss;
  u16* Oh = O + ((size_t)b * Ss * NH + h) * HD;
  const int wl = w * 16 + l16;       // this lane's q within the 64-row tile

  auto stage = [&](int k0) {
#pragma unroll
    for (int it = 0; it < 4; ++it) {
      int c = it * 256 + t;                       // 1024 chunks each
      int krow = c >> 4, kpc = c & 15;
      llds16(Kh + (size_t)(k0 + krow) * (NKV * HD) + (kpc ^ (krow & 7)) * 8, &Kts[c * 8]);
      int vrow = c >> 3, vpc = c & 7;
      llds16(Vh + (size_t)vrow * Ss + k0 + (vpc ^ (vrow & 7)) * 8, &Vts[c * 8]);
    }
  };

  for (int hf = 0; hf < 2; ++hf) {
    const int qb = hf ? (31 - (int)blockIdx.x) : (int)blockIdx.x;
    const int q0 = qb * 64;
    // Q fragment (loop-invariant): B-operand B[n=q=l16][k=d=q4*8+j]
    const int qrow = q0 + wl;
    short8 qf[4];
#pragma unroll
    for (int kt = 0; kt < 4; ++kt)
      qf[kt] = *(const short8*)&Qh[(size_t)qrow * (NH * HD) + kt * 32 + q4 * 8];

    floatx4 oacc[8];                  // O^T: d = td*16 + q4*4 + r, q = wl (this lane's)
#pragma unroll
    for (int i = 0; i < 8; ++i) oacc[i] = floatx4{0.f, 0.f, 0.f, 0.f};
    float m_i = -1e30f, l_p = 0.f;    // single q-row state per lane

    stage(0);   // safe: previous half's final barrier already passed

    for (int kb = 0; kb <= qb; ++kb) {
      __syncthreads();                 // staging of tile kb visible (drains vmcnt)

      // S^T = K Q^T : keys (rows) x 16 q (cols); per lane: keys tn*16+q4*4+r, q = wl
      floatx4 sc[4];
#pragma unroll
      for (int tn = 0; tn < 4; ++tn) sc[tn] = floatx4{0.f, 0.f, 0.f, 0.f};
#pragma unroll
      for (int kt = 0; kt < 4; ++kt)
#pragma unroll
        for (int tn = 0; tn < 4; ++tn) {
          short8 kfr = *(const short8*)&Kts[(tn * 16 + l16) * 128 + ((kt * 4 + q4) ^ sw8) * 8];
          sc[tn] = __builtin_amdgcn_mfma_f32_16x16x32_bf16(kfr, qf[kt], sc[tn], 0, 0, 0);
        }

      if (kb == qb) {  // diagonal: mask key > q (both tile-local)
#pragma unroll
        for (int tn = 0; tn < 4; ++tn) {
          int keyb = tn * 16 + q4 * 4;
#pragma unroll
          for (int r = 0; r < 4; ++r)
            if (keyb + r > wl) sc[tn][r] = -1e30f;
        }
      }

      // online softmax (base-2): lane reduces its 16 keys, then across quads (^16, ^32)
      float vmax = sc[0][0];
#pragma unroll
      for (int tn = 0; tn < 4; ++tn)
#pragma unroll
        for (int r = 0; r < 4; ++r) vmax = fmaxf(vmax, sc[tn][r]);
      vmax = fmaxf(vmax, __shfl_xor(vmax, 16));
      vmax = fmaxf(vmax, __shfl_xor(vmax, 32));
      float mnew = fmaxf(m_i, vmax);
      float alpha = __builtin_amdgcn_exp2f(m_i - mnew);
      m_i = mnew;
      float rs = 0.f;
#pragma unroll
      for (int tn = 0; tn < 4; ++tn)
#pragma unroll
        for (int r = 0; r < 4; ++r) {
          float p = __builtin_amdgcn_exp2f(sc[tn][r] - mnew);
          sc[tn][r] = p;
          rs += p;
        }
      l_p = l_p * alpha + rs;          // per-lane partial (quad-reduced at end)
#pragma unroll
      for (int td = 0; td < 8; ++td) oacc[td] *= alpha;

      // P^T store: lane's 4 consecutive keys per tn -> packed b64, row = wl (wave-private)
#pragma unroll
      for (int tn = 0; tn < 4; ++tn) {
        uint2 pk;
        pk.x = pkbf(sc[tn][0], sc[tn][1]);
        pk.y = pkbf(sc[tn][2], sc[tn][3]);
        *(uint2*)&Ps[(size_t)wl * 72 + tn * 16 + q4 * 4] = pk;
      }

      // O^T += V^T P^T
#pragma unroll
      for (int kt2 = 0; kt2 < 2; ++kt2) {
        short8 pfr = *(const short8*)&Ps[(size_t)wl * 72 + kt2 * 32 + q4 * 8];
#pragma unroll
        for (int td = 0; td < 8; ++td) {
          short8 vfr = *(const short8*)&Vts[(td * 16 + l16) * 64 + ((kt2 * 4 + q4) ^ sw8) * 8];
          oacc[td] = __builtin_amdgcn_mfma_f32_16x16x32_bf16(vfr, pfr, oacc[td], 0, 0, 0);
        }
      }

      __syncthreads();                 // all reads of Kts/Vts done
      if (kb < qb) stage((kb + 1) * 64);
    }

    // final denominator: reduce partials across quads
    float l = l_p;
    l += __shfl_xor(l, 16);
    l += __shfl_xor(l, 32);
    float linv = 1.f / l;
    // epilogue: lane owns q-row qrow; d = td*16 + q4*4 + r -> 4 consecutive bf16 = 8B store
#pragma unroll
    for (int td = 0; td < 8; ++td) {
      uint2 pk;
      pk.x = pkbf(oacc[td][0] * linv, oacc[td][1] * linv);
      pk.y = pkbf(oacc[td][2] * linv, oacc[td][3] * linv);
      *(uint2*)&Oh[(size_t)qrow * (NH * HD) + td * 16 + q4 * 4] = pk;
    }
  }
}

extern "C" void kernel_launch(void* const* d_in, const int* in_sizes, int n_in,
                              void* d_out, int out_size, void* d_ws, size_t ws_size,
                              hipStream_t stream) {
  (void)in_sizes; (void)n_in; (void)out_size; (void)ws_size;
  const float* x  = (const float*)d_in[0];
  const float* wq = (const float*)d_in[1];
  const float* wk = (const float*)d_in[2];
  const float* wv = (const float*)d_in[3];
  const float* wo = (const float*)d_in[4];
  float* out = (float*)d_out;

  char* ws = (char*)d_ws;
  size_t off = 0;
  auto alloc = [&](size_t bytes) {
    char* p = ws + off;
    off += (bytes + 255) & ~(size_t)255;
    return (void*)p;
  };
  u16* xb     = (u16*)alloc((size_t)MROWS * Hh * 2);        // reused as O (bf16) later
  u16* wqkvT  = (u16*)alloc((size_t)3072 * 2048 * 2);       // [wqT | wkT | wvT]
  u16* woT    = (u16*)alloc((size_t)2048 * 2048 * 2);
  u16* qkv16  = (u16*)alloc((size_t)MROWS * 3072 * 2);      // fused projection output, bf16
  u16* qb16   = (u16*)alloc((size_t)MROWS * 2048 * 2);
  u16* kb16   = (u16*)alloc((size_t)MROWS * 512 * 2);
  u16* vt16   = (u16*)alloc((size_t)MROWS * 512 * 2);
  u16* o16    = xb;  // xb dead after QKV projection

  // 1. prep: x->bf16 + all weight transposes (one launch)
  k_prep<<<dim3(8192 + 10240), dim3(256), 0, stream>>>(x, wq, wk, wv, wo, xb, wqkvT, woT);
  // 2. fused QKV projection -> bf16 (4096,3072)
  k_gemm<true><<<dim3(24, 32), dim3(256), 0, stream>>>(xb, wqkvT, qkv16, MROWS, 3072, 2048);
  // 3. post: RoPE Q+K + V transpose (one launch); Q scale folds 1/sqrt(HD)*log2(e)
  k_post<<<dim3(20480 + 2048), dim3(256), 0, stream>>>(
      qkv16, qb16, kb16, vt16, 0.08838834764831845f * 1.4426950408889634f);
  // 4. flash attention (single-buffered, 3 blocks/CU)
  k_flash<<<dim3(16, NH, Bb), dim3(256), 0, stream>>>(qb16, kb16, vt16, o16);
  // 5. output projection -> fp32 out
  k_gemm<false><<<dim3(16, 32), dim3(256), 0, stream>>>(o16, woT, out, MROWS, 2048, 2048);
}